// Round 13
// baseline (13001.614 us; speedup 1.0000x reference)
//
#include <hip/hip_runtime.h>

#define Bn 4
#define Tn 2048
#define Hn 512
#define En 512
#define Vn 32000
#define G3 1536
#define BT (Bn*Tn)

typedef __bf16 bf16x8 __attribute__((ext_vector_type(8)));
typedef float f32x4 __attribute__((ext_vector_type(4)));

__device__ __forceinline__ unsigned short f2bf(float f) {
  unsigned int u = __float_as_uint(f);
  u += 0x7fffu + ((u >> 16) & 1u);
  return (unsigned short)(u >> 16);
}

__device__ __forceinline__ void cvt4(const float* __restrict__ in,
                                     unsigned short* __restrict__ outp, size_t idx) {
  float4 f = *(const float4*)(in + idx * 4);
  uint2 o;
  o.x = (unsigned)f2bf(f.x) | ((unsigned)f2bf(f.y) << 16);
  o.y = (unsigned)f2bf(f.z) | ((unsigned)f2bf(f.w) << 16);
  *(uint2*)(outp + idx * 4) = o;
}

// ---------------- fused prep: weight cvts + embedding gather ----------------
// blocks [0,16000): Wfc cvt | [16000,16768): Wih | [16768,17024): Wq |
// [17024,17280): Wk | [17280,17536): Wv | [17536,19584): emb gather
__global__ __launch_bounds__(256) void prep_kernel(const float* __restrict__ Wfc,
                                                   unsigned short* __restrict__ wfcb,
                                                   const float* __restrict__ Wih,
                                                   unsigned short* __restrict__ wihb,
                                                   const float* __restrict__ Wq,
                                                   const float* __restrict__ Wk,
                                                   const float* __restrict__ Wv,
                                                   unsigned short* __restrict__ wqkvb,
                                                   const int* __restrict__ x,
                                                   const float* __restrict__ emb,
                                                   unsigned short* __restrict__ embb) {
  int b = blockIdx.x;
  int tid = threadIdx.x;
  if (b < 16000) {
    cvt4(Wfc, wfcb, (size_t)b * 256 + tid);
  } else if (b < 16768) {
    cvt4(Wih, wihb, (size_t)(b - 16000) * 256 + tid);
  } else if (b < 17024) {
    cvt4(Wq, wqkvb, (size_t)(b - 16768) * 256 + tid);
  } else if (b < 17280) {
    cvt4(Wk, wqkvb + 262144, (size_t)(b - 17024) * 256 + tid);
  } else if (b < 17536) {
    cvt4(Wv, wqkvb + 524288, (size_t)(b - 17280) * 256 + tid);
  } else {
    size_t idx = ((size_t)(b - 17536) * 256 + tid) * 8;
    int row = (int)(idx >> 9), e = (int)(idx & 511);
    const float* src = emb + (size_t)x[row] * En + e;
    float4 f0 = *(const float4*)(src);
    float4 f1 = *(const float4*)(src + 4);
    uint4 o;
    o.x = (unsigned)f2bf(f0.x) | ((unsigned)f2bf(f0.y) << 16);
    o.y = (unsigned)f2bf(f0.z) | ((unsigned)f2bf(f0.w) << 16);
    o.z = (unsigned)f2bf(f1.x) | ((unsigned)f2bf(f1.y) << 16);
    o.w = (unsigned)f2bf(f1.z) | ((unsigned)f2bf(f1.w) << 16);
    *(uint4*)(embb + idx) = o;
  }
}

// ---------------- xg = embb @ wihb^T + bih  (bf16 MFMA, fp32 out) ------------
__global__ __launch_bounds__(256) void xg_mm_kernel(const unsigned short* __restrict__ A,
                                                    const unsigned short* __restrict__ Bw,
                                                    const float* __restrict__ bias,
                                                    float* __restrict__ out) {
  __shared__ unsigned short a_lds[128 * 40];
  __shared__ unsigned short b_lds[128 * 40];
  int n0 = blockIdx.x * 128, m0 = blockIdx.y * 128;
  int tid = threadIdx.x;
  int wid = tid >> 6, lane = tid & 63;
  int wm = wid >> 1, wn = wid & 1;
  f32x4 acc[4][4];
#pragma unroll
  for (int mf = 0; mf < 4; ++mf)
#pragma unroll
    for (int nf = 0; nf < 4; ++nf) {
      acc[mf][nf][0] = 0.0f; acc[mf][nf][1] = 0.0f;
      acc[mf][nf][2] = 0.0f; acc[mf][nf][3] = 0.0f;
    }
  int kcol = (lane >> 4) * 8;
  int rbase = lane & 15;
  for (int k0 = 0; k0 < 512; k0 += 32) {
#pragma unroll
    for (int sidx = 0; sidx < 2; ++sidx) {
      int slot = tid + sidx * 256;
      int row = slot >> 2, c8 = (slot & 3) * 8;
      uint4 av = *(const uint4*)(A  + (size_t)(m0 + row) * 512 + k0 + c8);
      *(uint4*)&a_lds[row * 40 + c8] = av;
      uint4 bv = *(const uint4*)(Bw + (size_t)(n0 + row) * 512 + k0 + c8);
      *(uint4*)&b_lds[row * 40 + c8] = bv;
    }
    __syncthreads();
    bf16x8 af[4], bf[4];
#pragma unroll
    for (int mf = 0; mf < 4; ++mf)
      af[mf] = *(const bf16x8*)&a_lds[(wm*64 + mf*16 + rbase) * 40 + kcol];
#pragma unroll
    for (int nf = 0; nf < 4; ++nf)
      bf[nf] = *(const bf16x8*)&b_lds[(wn*64 + nf*16 + rbase) * 40 + kcol];
#pragma unroll
    for (int mf = 0; mf < 4; ++mf)
#pragma unroll
      for (int nf = 0; nf < 4; ++nf)
        acc[mf][nf] = __builtin_amdgcn_mfma_f32_16x16x32_bf16(af[mf], bf[nf], acc[mf][nf], 0, 0, 0);
    __syncthreads();
  }
  int rgrp = (lane >> 4) * 4;
#pragma unroll
  for (int mf = 0; mf < 4; ++mf)
#pragma unroll
    for (int nf = 0; nf < 4; ++nf) {
      int col = n0 + wn*64 + nf*16 + (lane & 15);
      float bc = bias[col];
#pragma unroll
      for (int i2 = 0; i2 < 4; ++i2) {
        int row = m0 + wm*64 + mf*16 + rgrp + i2;
        out[(size_t)row * G3 + col] = acc[mf][nf][i2] + bc;
      }
    }
}

// ---------------- {q,k,v} = hsb @ wqkvb^T + b  (bf16 MFMA, bf16 out) ---------
__global__ __launch_bounds__(256) void qkv_mm_kernel(const unsigned short* __restrict__ A,
                                                     const unsigned short* __restrict__ Bw,
                                                     const float* __restrict__ bq,
                                                     const float* __restrict__ bk,
                                                     const float* __restrict__ bv,
                                                     unsigned short* __restrict__ qb,
                                                     unsigned short* __restrict__ kb,
                                                     unsigned short* __restrict__ vb) {
  __shared__ unsigned short a_lds[128 * 40];
  __shared__ unsigned short b_lds[128 * 40];
  int n0 = blockIdx.x * 128, m0 = blockIdx.y * 128;
  int seg = n0 >> 9;                       // tile-uniform: 0=q 1=k 2=v
  const float* bias = (seg == 0) ? bq : (seg == 1) ? bk : bv;
  unsigned short* outp = (seg == 0) ? qb : (seg == 1) ? kb : vb;
  int nc0 = n0 & 511;
  int tid = threadIdx.x;
  int wid = tid >> 6, lane = tid & 63;
  int wm = wid >> 1, wn = wid & 1;
  f32x4 acc[4][4];
#pragma unroll
  for (int mf = 0; mf < 4; ++mf)
#pragma unroll
    for (int nf = 0; nf < 4; ++nf) {
      acc[mf][nf][0] = 0.0f; acc[mf][nf][1] = 0.0f;
      acc[mf][nf][2] = 0.0f; acc[mf][nf][3] = 0.0f;
    }
  int kcol = (lane >> 4) * 8;
  int rbase = lane & 15;
  for (int k0 = 0; k0 < 512; k0 += 32) {
#pragma unroll
    for (int sidx = 0; sidx < 2; ++sidx) {
      int slot = tid + sidx * 256;
      int row = slot >> 2, c8 = (slot & 3) * 8;
      uint4 av = *(const uint4*)(A  + (size_t)(m0 + row) * 512 + k0 + c8);
      *(uint4*)&a_lds[row * 40 + c8] = av;
      uint4 bv4 = *(const uint4*)(Bw + (size_t)(n0 + row) * 512 + k0 + c8);
      *(uint4*)&b_lds[row * 40 + c8] = bv4;
    }
    __syncthreads();
    bf16x8 af[4], bf[4];
#pragma unroll
    for (int mf = 0; mf < 4; ++mf)
      af[mf] = *(const bf16x8*)&a_lds[(wm*64 + mf*16 + rbase) * 40 + kcol];
#pragma unroll
    for (int nf = 0; nf < 4; ++nf)
      bf[nf] = *(const bf16x8*)&b_lds[(wn*64 + nf*16 + rbase) * 40 + kcol];
#pragma unroll
    for (int mf = 0; mf < 4; ++mf)
#pragma unroll
      for (int nf = 0; nf < 4; ++nf)
        acc[mf][nf] = __builtin_amdgcn_mfma_f32_16x16x32_bf16(af[mf], bf[nf], acc[mf][nf], 0, 0, 0);
    __syncthreads();
  }
  int rgrp = (lane >> 4) * 4;
#pragma unroll
  for (int mf = 0; mf < 4; ++mf)
#pragma unroll
    for (int nf = 0; nf < 4; ++nf) {
      int col = nc0 + wn*64 + nf*16 + (lane & 15);
      float bc = bias[col];
#pragma unroll
      for (int i2 = 0; i2 < 4; ++i2) {
        int row = m0 + wm*64 + mf*16 + rgrp + i2;
        outp[(size_t)row * Hn + col] = f2bf(acc[mf][nf][i2] + bc);
      }
    }
}

// ---------------- GRU scan: packed slots, 2-deep pipelined poll --------------
// 256 WGs (1/CU). WG g owns units {2g,2g+1}; wave w = batch w, decoupled.
// Exchange: per (t,batch) 256 u64 words; word m packs h[2m],h[2m+1], each f32
// with LOW MANTISSA BIT FORCED TO 1 as written-tag (memset-0 => not ready).
// Poll: TWO masked rounds in flight (absorb A / reissue A / absorb B /
// reissue B) -- halves the sampling period vs r12's single-round loop.
// Publish: lanes 0/1 store their own tagged u32 half directly (no shfl);
// consumer's per-half tag check makes the u64 view tear-safe.
__global__ __launch_bounds__(256, 1) void gru_kernel(const float* __restrict__ Whh,
                                                     const float* __restrict__ bhh,
                                                     const float* __restrict__ xg,
                                                     unsigned short* __restrict__ hsb,
                                                     unsigned long long* __restrict__ th) {
  __shared__ float w_lds[6][512];   // 12 KB, packed-order layout (see staging)
  int tid = threadIdx.x;
  int g = blockIdx.x;          // 0..255 == word index m for units {2g,2g+1}
  int jb = g * 2;
  int w = tid >> 6, lane = tid & 63;

  // w_lds[d][s*64+ln] = Whh_row_d[(s>>1)*128 + 2*ln + (s&1)]  (bijective map)
  for (int d = 0; d < 6; ++d) {
    const float* wr = Whh + (size_t)((d >> 1) * 512 + jb + (d & 1)) * 512;
    int e0 = tid, e1 = tid + 256;
    int s0 = e0 >> 6, l0 = e0 & 63;
    int s1 = e1 >> 6, l1 = e1 & 63;
    w_lds[d][e0] = wr[(s0 >> 1) * 128 + 2 * l0 + (s0 & 1)];
    w_lds[d][e1] = wr[(s1 >> 1) * 128 + 2 * l1 + (s1 & 1)];
  }
  float bh_r = 0.0f, bh_z = 0.0f, bh_n = 0.0f;
  if (lane < 2) {
    bh_r = bhh[jb + lane];
    bh_z = bhh[512 + jb + lane];
    bh_n = bhh[1024 + jb + lane];
  }
  float hown = 0.0f;   // lanes<2 of wave w: h for (batch w, unit jb+lane)
  unsigned* th32 = (unsigned*)th;
  __syncthreads();     // weights staged (only barrier in the kernel)

  const unsigned long long RDYM = 0x0000000100000001ULL;
  for (int t = 0; t < Tn; ++t) {
    // x-gate prefetch (independent of the poll; overlaps LLC latency)
    float xr = 0.0f, xz = 0.0f, xn = 0.0f;
    if (lane < 2) {
      size_t xb = ((size_t)(w * Tn + t)) * G3 + jb + lane;
      xr = xg[xb]; xz = xg[xb + 512]; xn = xg[xb + 1024];
    }
    float hlo[4], hhi[4];
    if (t > 0) {
      const unsigned long long* tp = th + (size_t)(t - 1) * 1024 + w * 256;
      unsigned long long A[4], B[4], v[4];
      unsigned rdy = 0;
#pragma unroll
      for (int q = 0; q < 4; ++q)
        A[q] = __hip_atomic_load(tp + q * 64 + lane, __ATOMIC_RELAXED,
                                 __HIP_MEMORY_SCOPE_AGENT);
#pragma unroll
      for (int q = 0; q < 4; ++q)
        B[q] = __hip_atomic_load(tp + q * 64 + lane, __ATOMIC_RELAXED,
                                 __HIP_MEMORY_SCOPE_AGENT);
      for (;;) {
        // absorb round A
#pragma unroll
        for (int q = 0; q < 4; ++q)
          if (!(rdy & (1u << q)) && ((A[q] & RDYM) == RDYM)) {
            v[q] = A[q]; rdy |= 1u << q;
          }
        if (__all(rdy == 15u)) break;
        // reissue round A (masked)
#pragma unroll
        for (int q = 0; q < 4; ++q)
          if (!(rdy & (1u << q)))
            A[q] = __hip_atomic_load(tp + q * 64 + lane, __ATOMIC_RELAXED,
                                     __HIP_MEMORY_SCOPE_AGENT);
        // absorb round B
#pragma unroll
        for (int q = 0; q < 4; ++q)
          if (!(rdy & (1u << q)) && ((B[q] & RDYM) == RDYM)) {
            v[q] = B[q]; rdy |= 1u << q;
          }
        if (__all(rdy == 15u)) break;
        // reissue round B (masked)
#pragma unroll
        for (int q = 0; q < 4; ++q)
          if (!(rdy & (1u << q)))
            B[q] = __hip_atomic_load(tp + q * 64 + lane, __ATOMIC_RELAXED,
                                     __HIP_MEMORY_SCOPE_AGENT);
      }
#pragma unroll
      for (int q = 0; q < 4; ++q) {
        hlo[q] = __uint_as_float((unsigned)v[q]);
        hhi[q] = __uint_as_float((unsigned)(v[q] >> 32));
      }
    } else {
#pragma unroll
      for (int q = 0; q < 4; ++q) { hlo[q] = 0.0f; hhi[q] = 0.0f; }
    }

    // 6 dots from packed-order LDS weights
    float p[6];
#pragma unroll
    for (int d = 0; d < 6; ++d) {
      float s = w_lds[d][lane] * hlo[0];
      s = fmaf(w_lds[d][64 + lane], hhi[0], s);
#pragma unroll
      for (int q = 1; q < 4; ++q) {
        s = fmaf(w_lds[d][(2 * q) * 64 + lane], hlo[q], s);
        s = fmaf(w_lds[d][(2 * q + 1) * 64 + lane], hhi[q], s);
      }
      p[d] = s;
    }

    // pair-merged butterfly: 3 chains; even lanes end with dt[2j], odd dt[2j+1]
    float mm[3];
#pragma unroll
    for (int j = 0; j < 3; ++j) {
      float a = p[2 * j], b = p[2 * j + 1];
      bool odd = (lane & 1);
      float send = odd ? a : b;
      float rx = __shfl_xor(send, 1);
      float m = (odd ? b : a) + rx;
      m += __shfl_xor(m, 2);
      m += __shfl_xor(m, 4);
      m += __shfl_xor(m, 8);
      m += __shfl_xor(m, 16);
      m += __shfl_xor(m, 32);
      mm[j] = m;
    }
    if (lane < 2) {
      float dr = mm[0], dz = mm[1], dn = mm[2];  // lane0: dt0/2/4, lane1: dt1/3/5
      float rr = __builtin_amdgcn_rcpf(1.0f + __expf(-(xr + dr + bh_r)));
      float zz = __builtin_amdgcn_rcpf(1.0f + __expf(-(xz + dz + bh_z)));
      float ta = xn + rr * (dn + bh_n);
      float nn = 1.0f - 2.0f * __builtin_amdgcn_rcpf(__expf(2.0f * ta) + 1.0f);
      hown = (1.0f - zz) * nn + zz * hown;
      // publish own tagged half directly (lane0 -> lo u32, lane1 -> hi u32)
      unsigned myb = __float_as_uint(hown) | 1u;
      __hip_atomic_store(th32 + (size_t)t * 2048 + (w * 256 + g) * 2 + lane, myb,
                         __ATOMIC_RELAXED, __HIP_MEMORY_SCOPE_AGENT);
      hsb[((size_t)w * Tn + t) * Hn + jb + lane] = f2bf(hown);
    }
  }
}

// ---------------- vT[b][e][t] = transpose of v[b][t][e]  (bf16 in/out) -------
__global__ __launch_bounds__(256) void vt_kernel(const unsigned short* __restrict__ v,
                                                 unsigned short* __restrict__ vT) {
  __shared__ unsigned short tl[64][80];   // row stride 160B (16B-aligned)
  int b = blockIdx.z;
  int t0 = blockIdx.x * 64, e0 = blockIdx.y * 64;
  int tid = threadIdx.x;
  int r = tid >> 2, c16 = (tid & 3) * 16;
  const unsigned short* src = v + (size_t)b * Tn * Hn + (size_t)(t0 + r) * Hn + e0 + c16;
  uint4 a0 = *(const uint4*)(src);
  uint4 a1 = *(const uint4*)(src + 8);
  *(uint4*)&tl[r][c16]     = a0;
  *(uint4*)&tl[r][c16 + 8] = a1;
  __syncthreads();
  unsigned short* dst = vT + (size_t)b * Hn * Tn + (size_t)(e0 + r) * Tn + t0 + c16;
  unsigned int o[8];
#pragma unroll
  for (int ii = 0; ii < 8; ++ii)
    o[ii] = (unsigned)tl[c16 + 2*ii][r] | ((unsigned)tl[c16 + 2*ii + 1][r] << 16);
  uint4 o0; o0.x = o[0]; o0.y = o[1]; o0.z = o[2]; o0.w = o[3];
  uint4 o1; o1.x = o[4]; o1.y = o[5]; o1.z = o[6]; o1.w = o[7];
  *(uint4*)(dst)     = o0;
  *(uint4*)(dst + 8) = o1;
}

// ---------------- scores = q @ k^T * scale  (bf16 MFMA, causal tile skip) ----
__global__ __launch_bounds__(256) void score_kernel(const unsigned short* __restrict__ qb,
                                                    const unsigned short* __restrict__ kbp,
                                                    float* __restrict__ s) {
  if (blockIdx.x > blockIdx.y) return;
  __shared__ unsigned short a_lds[128 * 40];
  __shared__ unsigned short b_lds[128 * 40];
  int b = blockIdx.z;
  int n0 = blockIdx.x * 128, m0 = blockIdx.y * 128;
  const unsigned short* A  = qb  + (size_t)b * Tn * Hn;
  const unsigned short* Bw = kbp + (size_t)b * Tn * Hn;
  int tid = threadIdx.x;
  int wid = tid >> 6, lane = tid & 63;
  int wm = wid >> 1, wn = wid & 1;
  f32x4 acc[4][4];
#pragma unroll
  for (int mf = 0; mf < 4; ++mf)
#pragma unroll
    for (int nf = 0; nf < 4; ++nf) {
      acc[mf][nf][0] = 0.0f; acc[mf][nf][1] = 0.0f;
      acc[mf][nf][2] = 0.0f; acc[mf][nf][3] = 0.0f;
    }
  int kcol = (lane >> 4) * 8;
  int rbase = lane & 15;
  for (int k0 = 0; k0 < Hn; k0 += 32) {
#pragma unroll
    for (int sidx = 0; sidx < 2; ++sidx) {
      int slot = tid + sidx * 256;
      int row = slot >> 2, c8 = (slot & 3) * 8;
      uint4 av = *(const uint4*)(A  + (size_t)(m0 + row) * Hn + k0 + c8);
      *(uint4*)&a_lds[row * 40 + c8] = av;
      uint4 bv = *(const uint4*)(Bw + (size_t)(n0 + row) * Hn + k0 + c8);
      *(uint4*)&b_lds[row * 40 + c8] = bv;
    }
    __syncthreads();
    bf16x8 af[4], bf[4];
#pragma unroll
    for (int mf = 0; mf < 4; ++mf)
      af[mf] = *(const bf16x8*)&a_lds[(wm*64 + mf*16 + rbase) * 40 + kcol];
#pragma unroll
    for (int nf = 0; nf < 4; ++nf)
      bf[nf] = *(const bf16x8*)&b_lds[(wn*64 + nf*16 + rbase) * 40 + kcol];
#pragma unroll
    for (int mf = 0; mf < 4; ++mf)
#pragma unroll
      for (int nf = 0; nf < 4; ++nf)
        acc[mf][nf] = __builtin_amdgcn_mfma_f32_16x16x32_bf16(af[mf], bf[nf], acc[mf][nf], 0, 0, 0);
    __syncthreads();
  }
  const float scale = 0.04419417382415922f;  // 1/sqrt(512)
  int rgrp = (lane >> 4) * 4;
#pragma unroll
  for (int mf = 0; mf < 4; ++mf)
#pragma unroll
    for (int nf = 0; nf < 4; ++nf) {
      int col = n0 + wn*64 + nf*16 + (lane & 15);
#pragma unroll
      for (int i2 = 0; i2 < 4; ++i2) {
        int row = m0 + wm*64 + mf*16 + rgrp + i2;
        s[(size_t)b*Tn*Tn + (size_t)row*Tn + col] = acc[mf][nf][i2] * scale;
      }
    }
}

// ---------------- causal softmax; fp32 in, bf16 out + zero-pad to tile edge --
__global__ __launch_bounds__(256) void softmax_kernel(float* __restrict__ s,
                                                      unsigned short* __restrict__ ab) {
  int row = blockIdx.x;
  int b = row >> 11, i = row & 2047;
  float* p = s + (size_t)b*Tn*Tn + (size_t)i*Tn;
  unsigned short* a = ab + ((size_t)b*Tn + i) * Tn;
  int len = i + 1;
  int padEnd = ((i >> 7) + 1) << 7;
  int tid = threadIdx.x;
  __shared__ float redm[4];
  __shared__ float reds[4];
  float m = -1e30f;
  for (int j = tid; j < len; j += 256) m = fmaxf(m, p[j]);
#pragma unroll
  for (int off = 32; off > 0; off >>= 1) m = fmaxf(m, __shfl_down(m, off));
  if ((tid & 63) == 0) redm[tid >> 6] = m;
  __syncthreads();
  if (tid == 0) redm[0] = fmaxf(fmaxf(redm[0], redm[1]), fmaxf(redm[2], redm[3]));
  __syncthreads();
  m = redm[0];
  float sum = 0.0f;
  for (int j = tid; j < len; j += 256) {
    float e = __expf(p[j] - m);
    p[j] = e;
    sum += e;
  }
#pragma unroll
  for (int off = 32; off > 0; off >>= 1) sum += __shfl_down(sum, off);
  if ((tid & 63) == 0) reds[tid >> 6] = sum;
  __syncthreads();
  if (tid == 0) reds[0] = reds[0] + reds[1] + reds[2] + reds[3];
  __syncthreads();
  float inv = 1.0f / reds[0];
  for (int j = tid; j < len; j += 256) a[j] = f2bf(p[j] * inv);
  for (int j = len + tid; j < padEnd; j += 256) a[j] = 0;
}

// ---------------- ctx = attn_bf16 @ vT^T  (bf16 MFMA, causal K bound) --------
__global__ __launch_bounds__(256) void ctx_kernel(const unsigned short* __restrict__ ab,
                                                  const unsigned short* __restrict__ vT,
                                                  unsigned short* __restrict__ ctxb) {
  __shared__ unsigned short a_lds[128 * 40];
  __shared__ unsigned short b_lds[128 * 40];
  int b = blockIdx.z;
  int n0 = blockIdx.x * 128, m0 = blockIdx.y * 128;
  int kmax = (blockIdx.y + 1) * 128;
  const unsigned short* A  = ab + (size_t)b * Tn * Tn;
  const unsigned short* Bw = vT + (size_t)b * Hn * Tn;
  int tid = threadIdx.x;
  int wid = tid >> 6, lane = tid & 63;
  int wm = wid >> 1, wn = wid & 1;
  f32x4 acc[4][4];
#pragma unroll
  for (int mf = 0; mf < 4; ++mf)
#pragma unroll
    for (int nf = 0; nf < 4; ++nf) {
      acc[mf][nf][0] = 0.0f; acc[mf][nf][1] = 0.0f;
      acc[mf][nf][2] = 0.0f; acc[mf][nf][3] = 0.0f;
    }
  int kcol = (lane >> 4) * 8;
  int rbase = lane & 15;
  for (int k0 = 0; k0 < kmax; k0 += 32) {
#pragma unroll
    for (int sidx = 0; sidx < 2; ++sidx) {
      int slot = tid + sidx * 256;
      int row = slot >> 2, c8 = (slot & 3) * 8;
      uint4 av = *(const uint4*)(A  + (size_t)(m0 + row) * Tn + k0 + c8);
      *(uint4*)&a_lds[row * 40 + c8] = av;
      uint4 bv = *(const uint4*)(Bw + (size_t)(n0 + row) * Tn + k0 + c8);
      *(uint4*)&b_lds[row * 40 + c8] = bv;
    }
    __syncthreads();
    bf16x8 af[4], bf[4];
#pragma unroll
    for (int mf = 0; mf < 4; ++mf)
      af[mf] = *(const bf16x8*)&a_lds[(wm*64 + mf*16 + rbase) * 40 + kcol];
#pragma unroll
    for (int nf = 0; nf < 4; ++nf)
      bf[nf] = *(const bf16x8*)&b_lds[(wn*64 + nf*16 + rbase) * 40 + kcol];
#pragma unroll
    for (int mf = 0; mf < 4; ++mf)
#pragma unroll
      for (int nf = 0; nf < 4; ++nf)
        acc[mf][nf] = __builtin_amdgcn_mfma_f32_16x16x32_bf16(af[mf], bf[nf], acc[mf][nf], 0, 0, 0);
    __syncthreads();
  }
  int rgrp = (lane >> 4) * 4;
#pragma unroll
  for (int mf = 0; mf < 4; ++mf)
#pragma unroll
    for (int nf = 0; nf < 4; ++nf) {
      int col = n0 + wn*64 + nf*16 + (lane & 15);
#pragma unroll
      for (int i2 = 0; i2 < 4; ++i2) {
        int row = m0 + wm*64 + mf*16 + rgrp + i2;
        ctxb[((size_t)b*Tn + row) * Hn + col] = f2bf(acc[mf][nf][i2]);
      }
    }
}

// ---------------- logits = ctx_bf16 @ Wfc_bf16^T + bfc  (MFMA 16x16x32) ------
__global__ __launch_bounds__(256) void logits_kernel(const unsigned short* __restrict__ A,
                                                     const unsigned short* __restrict__ Bw,
                                                     const float* __restrict__ bias,
                                                     float* __restrict__ out) {
  __shared__ unsigned short a_lds[128 * 40];
  __shared__ unsigned short b_lds[128 * 40];
  int n0 = blockIdx.x * 128, m0 = blockIdx.y * 128;
  int tid = threadIdx.x;
  int wid = tid >> 6, lane = tid & 63;
  int wm = wid >> 1, wn = wid & 1;
  f32x4 acc[4][4];
#pragma unroll
  for (int mf = 0; mf < 4; ++mf)
#pragma unroll
    for (int nf = 0; nf < 4; ++nf) {
      acc[mf][nf][0] = 0.0f; acc[mf][nf][1] = 0.0f;
      acc[mf][nf][2] = 0.0f; acc[mf][nf][3] = 0.0f;
    }
  int kcol = (lane >> 4) * 8;
  int rbase = lane & 15;
  for (int k0 = 0; k0 < 512; k0 += 32) {
#pragma unroll
    for (int sidx = 0; sidx < 2; ++sidx) {
      int slot = tid + sidx * 256;
      int row = slot >> 2, c8 = (slot & 3) * 8;
      uint4 av = *(const uint4*)(A  + (size_t)(m0 + row) * 512 + k0 + c8);
      *(uint4*)&a_lds[row * 40 + c8] = av;
      uint4 bv = *(const uint4*)(Bw + (size_t)(n0 + row) * 512 + k0 + c8);
      *(uint4*)&b_lds[row * 40 + c8] = bv;
    }
    __syncthreads();
    bf16x8 af[4], bf[4];
#pragma unroll
    for (int mf = 0; mf < 4; ++mf)
      af[mf] = *(const bf16x8*)&a_lds[(wm*64 + mf*16 + rbase) * 40 + kcol];
#pragma unroll
    for (int nf = 0; nf < 4; ++nf)
      bf[nf] = *(const bf16x8*)&b_lds[(wn*64 + nf*16 + rbase) * 40 + kcol];
#pragma unroll
    for (int mf = 0; mf < 4; ++mf)
#pragma unroll
      for (int nf = 0; nf < 4; ++nf)
        acc[mf][nf] = __builtin_amdgcn_mfma_f32_16x16x32_bf16(af[mf], bf[nf], acc[mf][nf], 0, 0, 0);
    __syncthreads();
  }
  int rgrp = (lane >> 4) * 4;
#pragma unroll
  for (int mf = 0; mf < 4; ++mf)
#pragma unroll
    for (int nf = 0; nf < 4; ++nf) {
      int col = n0 + wn*64 + nf*16 + (lane & 15);
      float bc = bias[col];
#pragma unroll
      for (int i2 = 0; i2 < 4; ++i2) {
        int row = m0 + wm*64 + mf*16 + rgrp + i2;
        out[(size_t)row * Vn + col] = acc[mf][nf][i2] + bc;
      }
    }
}

extern "C" void kernel_launch(void* const* d_in, const int* in_sizes, int n_in,
                              void* d_out, int out_size, void* d_ws, size_t ws_size,
                              hipStream_t stream) {
  const int*   x   = (const int*)d_in[0];
  const float* emb = (const float*)d_in[1];
  const float* Wih = (const float*)d_in[2];
  const float* Whh = (const float*)d_in[3];
  const float* bih = (const float*)d_in[4];
  const float* bhh = (const float*)d_in[5];
  const float* Wq  = (const float*)d_in[6];
  const float* bq  = (const float*)d_in[7];
  const float* Wk  = (const float*)d_in[8];
  const float* bk  = (const float*)d_in[9];
  const float* Wv  = (const float*)d_in[10];
  const float* bv  = (const float*)d_in[11];
  const float* Wfc = (const float*)d_in[12];
  const float* bfc = (const float*)d_in[13];
  float* out = (float*)d_out;

  char* ws = (char*)d_ws;
  unsigned short* hsb   = (unsigned short*)(ws);               //  8 MB [0,8M)
  unsigned short* qb    = (unsigned short*)(ws + 8388608);     //  8 MB
  unsigned short* kb    = (unsigned short*)(ws + 16777216);    //  8 MB
  unsigned short* vb    = (unsigned short*)(ws + 25165824);    //  8 MB
  unsigned short* vTb   = (unsigned short*)(ws + 33554432);    //  8 MB
  unsigned short* ctxb  = (unsigned short*)(ws + 41943040);    //  8 MB
  unsigned short* wfcb  = (unsigned short*)(ws + 50331648);    // 32 MB
  unsigned short* embb  = (unsigned short*)(ws + 83886080);    //  8 MB
  unsigned short* wihb  = (unsigned short*)(ws + 92274688);    // 1.5 MB
  unsigned short* wqkvb = (unsigned short*)(ws + 93847552);    // 1.5 MB -> ends ~95.4 MB

  // d_out (1,048,576,000 B) doubles as scratch: scores(fp32) + xg + packed-h +
  // attn(bf16); all fully consumed before logits_kernel overwrites the buffer.
  float* scores = out;                                                         // [0, 67,108,864)
  float* xg = (float*)((char*)d_out + 67108864);                               // 50,331,648 B
  unsigned long long* th = (unsigned long long*)((char*)d_out + 117440512);    // 16,777,216 B
  unsigned short* attnb  = (unsigned short*)((char*)d_out + 150994944);        // 33,554,432 B

  hipMemsetAsync(th, 0, (size_t)Tn * 1024 * 8, stream);       // clear tags (replay-safe)
  prep_kernel<<<19584, 256, 0, stream>>>(Wfc, wfcb, Wih, wihb, Wq, Wk, Wv,
                                         wqkvb, x, emb, embb);
  xg_mm_kernel<<<dim3(12, 64), 256, 0, stream>>>(embb, wihb, bih, xg);
  gru_kernel<<<256, 256, 0, stream>>>(Whh, bhh, xg, hsb, th);
  qkv_mm_kernel<<<dim3(12, 64), 256, 0, stream>>>(hsb, wqkvb, bq, bk, bv, qb, kb, vb);
  vt_kernel<<<dim3(32, 8, Bn), 256, 0, stream>>>(vb, vTb);
  score_kernel<<<dim3(16, 16, Bn), 256, 0, stream>>>(qb, kb, scores);
  softmax_kernel<<<BT, 256, 0, stream>>>(scores, attnb);
  ctx_kernel<<<dim3(4, 16, Bn), 256, 0, stream>>>(attnb, vTb, ctxb);
  logits_kernel<<<dim3(250, 64), 256, 0, stream>>>(ctxb, wfcb, bfc, out);
}

// Round 14
// 4536.745 us; speedup vs baseline: 2.8658x; 2.8658x over previous
//
#include <hip/hip_runtime.h>

#define Bn 4
#define Tn 2048
#define Hn 512
#define En 512
#define Vn 32000
#define G3 1536
#define BT (Bn*Tn)

typedef __bf16 bf16x8 __attribute__((ext_vector_type(8)));
typedef float f32x4 __attribute__((ext_vector_type(4)));

__device__ __forceinline__ unsigned short f2bf(float f) {
  unsigned int u = __float_as_uint(f);
  u += 0x7fffu + ((u >> 16) & 1u);
  return (unsigned short)(u >> 16);
}

__device__ __forceinline__ void cvt4(const float* __restrict__ in,
                                     unsigned short* __restrict__ outp, size_t idx) {
  float4 f = *(const float4*)(in + idx * 4);
  uint2 o;
  o.x = (unsigned)f2bf(f.x) | ((unsigned)f2bf(f.y) << 16);
  o.y = (unsigned)f2bf(f.z) | ((unsigned)f2bf(f.w) << 16);
  *(uint2*)(outp + idx * 4) = o;
}

// ---------------- fused prep: weight cvts + embedding gather ----------------
// blocks [0,16000): Wfc cvt | [16000,16768): Wih | [16768,17024): Wq |
// [17024,17280): Wk | [17280,17536): Wv | [17536,19584): emb gather
__global__ __launch_bounds__(256) void prep_kernel(const float* __restrict__ Wfc,
                                                   unsigned short* __restrict__ wfcb,
                                                   const float* __restrict__ Wih,
                                                   unsigned short* __restrict__ wihb,
                                                   const float* __restrict__ Wq,
                                                   const float* __restrict__ Wk,
                                                   const float* __restrict__ Wv,
                                                   unsigned short* __restrict__ wqkvb,
                                                   const int* __restrict__ x,
                                                   const float* __restrict__ emb,
                                                   unsigned short* __restrict__ embb) {
  int b = blockIdx.x;
  int tid = threadIdx.x;
  if (b < 16000) {
    cvt4(Wfc, wfcb, (size_t)b * 256 + tid);
  } else if (b < 16768) {
    cvt4(Wih, wihb, (size_t)(b - 16000) * 256 + tid);
  } else if (b < 17024) {
    cvt4(Wq, wqkvb, (size_t)(b - 16768) * 256 + tid);
  } else if (b < 17280) {
    cvt4(Wk, wqkvb + 262144, (size_t)(b - 17024) * 256 + tid);
  } else if (b < 17536) {
    cvt4(Wv, wqkvb + 524288, (size_t)(b - 17280) * 256 + tid);
  } else {
    size_t idx = ((size_t)(b - 17536) * 256 + tid) * 8;
    int row = (int)(idx >> 9), e = (int)(idx & 511);
    const float* src = emb + (size_t)x[row] * En + e;
    float4 f0 = *(const float4*)(src);
    float4 f1 = *(const float4*)(src + 4);
    uint4 o;
    o.x = (unsigned)f2bf(f0.x) | ((unsigned)f2bf(f0.y) << 16);
    o.y = (unsigned)f2bf(f0.z) | ((unsigned)f2bf(f0.w) << 16);
    o.z = (unsigned)f2bf(f1.x) | ((unsigned)f2bf(f1.y) << 16);
    o.w = (unsigned)f2bf(f1.z) | ((unsigned)f2bf(f1.w) << 16);
    *(uint4*)(embb + idx) = o;
  }
}

// ---------------- xg = embb @ wihb^T + bih  (bf16 MFMA, fp32 out) ------------
__global__ __launch_bounds__(256) void xg_mm_kernel(const unsigned short* __restrict__ A,
                                                    const unsigned short* __restrict__ Bw,
                                                    const float* __restrict__ bias,
                                                    float* __restrict__ out) {
  __shared__ unsigned short a_lds[128 * 40];
  __shared__ unsigned short b_lds[128 * 40];
  int n0 = blockIdx.x * 128, m0 = blockIdx.y * 128;
  int tid = threadIdx.x;
  int wid = tid >> 6, lane = tid & 63;
  int wm = wid >> 1, wn = wid & 1;
  f32x4 acc[4][4];
#pragma unroll
  for (int mf = 0; mf < 4; ++mf)
#pragma unroll
    for (int nf = 0; nf < 4; ++nf) {
      acc[mf][nf][0] = 0.0f; acc[mf][nf][1] = 0.0f;
      acc[mf][nf][2] = 0.0f; acc[mf][nf][3] = 0.0f;
    }
  int kcol = (lane >> 4) * 8;
  int rbase = lane & 15;
  for (int k0 = 0; k0 < 512; k0 += 32) {
#pragma unroll
    for (int sidx = 0; sidx < 2; ++sidx) {
      int slot = tid + sidx * 256;
      int row = slot >> 2, c8 = (slot & 3) * 8;
      uint4 av = *(const uint4*)(A  + (size_t)(m0 + row) * 512 + k0 + c8);
      *(uint4*)&a_lds[row * 40 + c8] = av;
      uint4 bv = *(const uint4*)(Bw + (size_t)(n0 + row) * 512 + k0 + c8);
      *(uint4*)&b_lds[row * 40 + c8] = bv;
    }
    __syncthreads();
    bf16x8 af[4], bf[4];
#pragma unroll
    for (int mf = 0; mf < 4; ++mf)
      af[mf] = *(const bf16x8*)&a_lds[(wm*64 + mf*16 + rbase) * 40 + kcol];
#pragma unroll
    for (int nf = 0; nf < 4; ++nf)
      bf[nf] = *(const bf16x8*)&b_lds[(wn*64 + nf*16 + rbase) * 40 + kcol];
#pragma unroll
    for (int mf = 0; mf < 4; ++mf)
#pragma unroll
      for (int nf = 0; nf < 4; ++nf)
        acc[mf][nf] = __builtin_amdgcn_mfma_f32_16x16x32_bf16(af[mf], bf[nf], acc[mf][nf], 0, 0, 0);
    __syncthreads();
  }
  int rgrp = (lane >> 4) * 4;
#pragma unroll
  for (int mf = 0; mf < 4; ++mf)
#pragma unroll
    for (int nf = 0; nf < 4; ++nf) {
      int col = n0 + wn*64 + nf*16 + (lane & 15);
      float bc = bias[col];
#pragma unroll
      for (int i2 = 0; i2 < 4; ++i2) {
        int row = m0 + wm*64 + mf*16 + rgrp + i2;
        out[(size_t)row * G3 + col] = acc[mf][nf][i2] + bc;
      }
    }
}

// ---------------- {q,k,v} = hsb @ wqkvb^T + b  (bf16 MFMA, bf16 out) ---------
__global__ __launch_bounds__(256) void qkv_mm_kernel(const unsigned short* __restrict__ A,
                                                     const unsigned short* __restrict__ Bw,
                                                     const float* __restrict__ bq,
                                                     const float* __restrict__ bk,
                                                     const float* __restrict__ bv,
                                                     unsigned short* __restrict__ qb,
                                                     unsigned short* __restrict__ kb,
                                                     unsigned short* __restrict__ vb) {
  __shared__ unsigned short a_lds[128 * 40];
  __shared__ unsigned short b_lds[128 * 40];
  int n0 = blockIdx.x * 128, m0 = blockIdx.y * 128;
  int seg = n0 >> 9;                       // tile-uniform: 0=q 1=k 2=v
  const float* bias = (seg == 0) ? bq : (seg == 1) ? bk : bv;
  unsigned short* outp = (seg == 0) ? qb : (seg == 1) ? kb : vb;
  int nc0 = n0 & 511;
  int tid = threadIdx.x;
  int wid = tid >> 6, lane = tid & 63;
  int wm = wid >> 1, wn = wid & 1;
  f32x4 acc[4][4];
#pragma unroll
  for (int mf = 0; mf < 4; ++mf)
#pragma unroll
    for (int nf = 0; nf < 4; ++nf) {
      acc[mf][nf][0] = 0.0f; acc[mf][nf][1] = 0.0f;
      acc[mf][nf][2] = 0.0f; acc[mf][nf][3] = 0.0f;
    }
  int kcol = (lane >> 4) * 8;
  int rbase = lane & 15;
  for (int k0 = 0; k0 < 512; k0 += 32) {
#pragma unroll
    for (int sidx = 0; sidx < 2; ++sidx) {
      int slot = tid + sidx * 256;
      int row = slot >> 2, c8 = (slot & 3) * 8;
      uint4 av = *(const uint4*)(A  + (size_t)(m0 + row) * 512 + k0 + c8);
      *(uint4*)&a_lds[row * 40 + c8] = av;
      uint4 bv4 = *(const uint4*)(Bw + (size_t)(n0 + row) * 512 + k0 + c8);
      *(uint4*)&b_lds[row * 40 + c8] = bv4;
    }
    __syncthreads();
    bf16x8 af[4], bf[4];
#pragma unroll
    for (int mf = 0; mf < 4; ++mf)
      af[mf] = *(const bf16x8*)&a_lds[(wm*64 + mf*16 + rbase) * 40 + kcol];
#pragma unroll
    for (int nf = 0; nf < 4; ++nf)
      bf[nf] = *(const bf16x8*)&b_lds[(wn*64 + nf*16 + rbase) * 40 + kcol];
#pragma unroll
    for (int mf = 0; mf < 4; ++mf)
#pragma unroll
      for (int nf = 0; nf < 4; ++nf)
        acc[mf][nf] = __builtin_amdgcn_mfma_f32_16x16x32_bf16(af[mf], bf[nf], acc[mf][nf], 0, 0, 0);
    __syncthreads();
  }
  int rgrp = (lane >> 4) * 4;
#pragma unroll
  for (int mf = 0; mf < 4; ++mf)
#pragma unroll
    for (int nf = 0; nf < 4; ++nf) {
      int col = nc0 + wn*64 + nf*16 + (lane & 15);
      float bc = bias[col];
#pragma unroll
      for (int i2 = 0; i2 < 4; ++i2) {
        int row = m0 + wm*64 + mf*16 + rgrp + i2;
        outp[(size_t)row * Hn + col] = f2bf(acc[mf][nf][i2] + bc);
      }
    }
}

// ---------------- GRU scan: packed 2-value slots, tight poll, merged reduce --
// 256 WGs (1/CU). WG g owns units {2g,2g+1}; wave w = batch w, decoupled.
// Exchange: per (t,batch) 256 u64 words; word m packs h[2m],h[2m+1], each f32
// with LOW MANTISSA BIT FORCED TO 1 as written-tag (memset-0 => not ready;
// rel err 1.2e-7). Poll loop is TIGHT (4 masked loads + 4 checks, nothing
// else -- r11 FMA-under-poll and r13 2-deep poll both regressed by
// lengthening the loop body / inflating poll traffic). FMAs after poll from
// packed-order LDS weights; pair-merged butterfly (3 chains).
__global__ __launch_bounds__(256, 1) void gru_kernel(const float* __restrict__ Whh,
                                                     const float* __restrict__ bhh,
                                                     const float* __restrict__ xg,
                                                     unsigned short* __restrict__ hsb,
                                                     unsigned long long* __restrict__ th) {
  __shared__ float w_lds[6][512];   // 12 KB, packed-order layout (see staging)
  int tid = threadIdx.x;
  int g = blockIdx.x;          // 0..255 == word index m for units {2g,2g+1}
  int jb = g * 2;
  int w = tid >> 6, lane = tid & 63;

  // w_lds[d][s*64+ln] = Whh_row_d[(s>>1)*128 + 2*ln + (s&1)]  (bijective map)
  // FMA slot (2q)*64+lane pairs with word m=q*64+lane's lo value h[2m];
  // slot (2q+1)*64+lane with its hi value h[2m+1].
  for (int d = 0; d < 6; ++d) {
    const float* wr = Whh + (size_t)((d >> 1) * 512 + jb + (d & 1)) * 512;
    int e0 = tid, e1 = tid + 256;
    int s0 = e0 >> 6, l0 = e0 & 63;
    int s1 = e1 >> 6, l1 = e1 & 63;
    w_lds[d][e0] = wr[(s0 >> 1) * 128 + 2 * l0 + (s0 & 1)];
    w_lds[d][e1] = wr[(s1 >> 1) * 128 + 2 * l1 + (s1 & 1)];
  }
  float bh_r = 0.0f, bh_z = 0.0f, bh_n = 0.0f;
  if (lane < 2) {
    bh_r = bhh[jb + lane];
    bh_z = bhh[512 + jb + lane];
    bh_n = bhh[1024 + jb + lane];
  }
  float hown = 0.0f;   // lanes<2 of wave w: h for (batch w, unit jb+lane)
  __syncthreads();     // weights staged (only barrier in the kernel)

  const unsigned long long RDYM = 0x0000000100000001ULL;
  for (int t = 0; t < Tn; ++t) {
    // x-gate prefetch (independent of the poll; overlaps LLC latency)
    float xr = 0.0f, xz = 0.0f, xn = 0.0f;
    if (lane < 2) {
      size_t xb = ((size_t)(w * Tn + t)) * G3 + jb + lane;
      xr = xg[xb]; xz = xg[xb + 512]; xn = xg[xb + 1024];
    }
    float hlo[4], hhi[4];
    if (t > 0) {
      const unsigned long long* tp = th + (size_t)(t - 1) * 1024 + w * 256;
      unsigned long long v[4];
      unsigned rdy = 0;           // per-lane bitmask of confirmed words
      do {
#pragma unroll
        for (int q = 0; q < 4; ++q)
          if (!(rdy & (1u << q)))
            v[q] = __hip_atomic_load(tp + q * 64 + lane, __ATOMIC_RELAXED,
                                     __HIP_MEMORY_SCOPE_AGENT);
#pragma unroll
        for (int q = 0; q < 4; ++q)
          if ((v[q] & RDYM) == RDYM) rdy |= 1u << q;
      } while (!__all(rdy == 15u));
#pragma unroll
      for (int q = 0; q < 4; ++q) {
        hlo[q] = __uint_as_float((unsigned)v[q]);
        hhi[q] = __uint_as_float((unsigned)(v[q] >> 32));
      }
    } else {
#pragma unroll
      for (int q = 0; q < 4; ++q) { hlo[q] = 0.0f; hhi[q] = 0.0f; }
    }

    // 6 dots from packed-order LDS weights (after poll; tight dependency-free)
    float p[6];
#pragma unroll
    for (int d = 0; d < 6; ++d) {
      float s = w_lds[d][lane] * hlo[0];
      s = fmaf(w_lds[d][64 + lane], hhi[0], s);
#pragma unroll
      for (int q = 1; q < 4; ++q) {
        s = fmaf(w_lds[d][(2 * q) * 64 + lane], hlo[q], s);
        s = fmaf(w_lds[d][(2 * q + 1) * 64 + lane], hhi[q], s);
      }
      p[d] = s;
    }

    // pair-merged butterfly: 3 chains; even lanes end with dt[2j], odd dt[2j+1]
    float mm[3];
#pragma unroll
    for (int j = 0; j < 3; ++j) {
      float a = p[2 * j], b = p[2 * j + 1];
      bool odd = (lane & 1);
      float send = odd ? a : b;
      float rx = __shfl_xor(send, 1);
      float m = (odd ? b : a) + rx;
      m += __shfl_xor(m, 2);
      m += __shfl_xor(m, 4);
      m += __shfl_xor(m, 8);
      m += __shfl_xor(m, 16);
      m += __shfl_xor(m, 32);
      mm[j] = m;
    }
    if (lane < 2) {
      float dr = mm[0], dz = mm[1], dn = mm[2];  // lane0: dt0/2/4, lane1: dt1/3/5
      float rr = __builtin_amdgcn_rcpf(1.0f + __expf(-(xr + dr + bh_r)));
      float zz = __builtin_amdgcn_rcpf(1.0f + __expf(-(xz + dz + bh_z)));
      float ta = xn + rr * (dn + bh_n);
      float nn = 1.0f - 2.0f * __builtin_amdgcn_rcpf(__expf(2.0f * ta) + 1.0f);
      hown = (1.0f - zz) * nn + zz * hown;
    }
    // pack both units into one word (lane0 <- lane1's bits) and publish once
    unsigned myb = __float_as_uint(hown) | 1u;
    unsigned other = __shfl(myb, 1);
    if (lane == 0) {
      unsigned long long pk = ((unsigned long long)other << 32) | myb;
      __hip_atomic_store(th + (size_t)t * 1024 + w * 256 + g, pk,
                         __ATOMIC_RELAXED, __HIP_MEMORY_SCOPE_AGENT);
    }
    if (lane < 2)
      hsb[((size_t)w * Tn + t) * Hn + jb + lane] = f2bf(hown);
  }
}

// ---------------- vT[b][e][t] = transpose of v[b][t][e]  (bf16 in/out) -------
__global__ __launch_bounds__(256) void vt_kernel(const unsigned short* __restrict__ v,
                                                 unsigned short* __restrict__ vT) {
  __shared__ unsigned short tl[64][80];   // row stride 160B (16B-aligned)
  int b = blockIdx.z;
  int t0 = blockIdx.x * 64, e0 = blockIdx.y * 64;
  int tid = threadIdx.x;
  int r = tid >> 2, c16 = (tid & 3) * 16;
  const unsigned short* src = v + (size_t)b * Tn * Hn + (size_t)(t0 + r) * Hn + e0 + c16;
  uint4 a0 = *(const uint4*)(src);
  uint4 a1 = *(const uint4*)(src + 8);
  *(uint4*)&tl[r][c16]     = a0;
  *(uint4*)&tl[r][c16 + 8] = a1;
  __syncthreads();
  unsigned short* dst = vT + (size_t)b * Hn * Tn + (size_t)(e0 + r) * Tn + t0 + c16;
  unsigned int o[8];
#pragma unroll
  for (int ii = 0; ii < 8; ++ii)
    o[ii] = (unsigned)tl[c16 + 2*ii][r] | ((unsigned)tl[c16 + 2*ii + 1][r] << 16);
  uint4 o0; o0.x = o[0]; o0.y = o[1]; o0.z = o[2]; o0.w = o[3];
  uint4 o1; o1.x = o[4]; o1.y = o[5]; o1.z = o[6]; o1.w = o[7];
  *(uint4*)(dst)     = o0;
  *(uint4*)(dst + 8) = o1;
}

// ---------------- scores = q @ k^T * scale  (bf16 MFMA, causal tile skip) ----
__global__ __launch_bounds__(256) void score_kernel(const unsigned short* __restrict__ qb,
                                                    const unsigned short* __restrict__ kbp,
                                                    float* __restrict__ s) {
  if (blockIdx.x > blockIdx.y) return;
  __shared__ unsigned short a_lds[128 * 40];
  __shared__ unsigned short b_lds[128 * 40];
  int b = blockIdx.z;
  int n0 = blockIdx.x * 128, m0 = blockIdx.y * 128;
  const unsigned short* A  = qb  + (size_t)b * Tn * Hn;
  const unsigned short* Bw = kbp + (size_t)b * Tn * Hn;
  int tid = threadIdx.x;
  int wid = tid >> 6, lane = tid & 63;
  int wm = wid >> 1, wn = wid & 1;
  f32x4 acc[4][4];
#pragma unroll
  for (int mf = 0; mf < 4; ++mf)
#pragma unroll
    for (int nf = 0; nf < 4; ++nf) {
      acc[mf][nf][0] = 0.0f; acc[mf][nf][1] = 0.0f;
      acc[mf][nf][2] = 0.0f; acc[mf][nf][3] = 0.0f;
    }
  int kcol = (lane >> 4) * 8;
  int rbase = lane & 15;
  for (int k0 = 0; k0 < Hn; k0 += 32) {
#pragma unroll
    for (int sidx = 0; sidx < 2; ++sidx) {
      int slot = tid + sidx * 256;
      int row = slot >> 2, c8 = (slot & 3) * 8;
      uint4 av = *(const uint4*)(A  + (size_t)(m0 + row) * Hn + k0 + c8);
      *(uint4*)&a_lds[row * 40 + c8] = av;
      uint4 bv = *(const uint4*)(Bw + (size_t)(n0 + row) * Hn + k0 + c8);
      *(uint4*)&b_lds[row * 40 + c8] = bv;
    }
    __syncthreads();
    bf16x8 af[4], bf[4];
#pragma unroll
    for (int mf = 0; mf < 4; ++mf)
      af[mf] = *(const bf16x8*)&a_lds[(wm*64 + mf*16 + rbase) * 40 + kcol];
#pragma unroll
    for (int nf = 0; nf < 4; ++nf)
      bf[nf] = *(const bf16x8*)&b_lds[(wn*64 + nf*16 + rbase) * 40 + kcol];
#pragma unroll
    for (int mf = 0; mf < 4; ++mf)
#pragma unroll
      for (int nf = 0; nf < 4; ++nf)
        acc[mf][nf] = __builtin_amdgcn_mfma_f32_16x16x32_bf16(af[mf], bf[nf], acc[mf][nf], 0, 0, 0);
    __syncthreads();
  }
  const float scale = 0.04419417382415922f;  // 1/sqrt(512)
  int rgrp = (lane >> 4) * 4;
#pragma unroll
  for (int mf = 0; mf < 4; ++mf)
#pragma unroll
    for (int nf = 0; nf < 4; ++nf) {
      int col = n0 + wn*64 + nf*16 + (lane & 15);
#pragma unroll
      for (int i2 = 0; i2 < 4; ++i2) {
        int row = m0 + wm*64 + mf*16 + rgrp + i2;
        s[(size_t)b*Tn*Tn + (size_t)row*Tn + col] = acc[mf][nf][i2] * scale;
      }
    }
}

// ---------------- causal softmax; fp32 in, bf16 out + zero-pad to tile edge --
__global__ __launch_bounds__(256) void softmax_kernel(float* __restrict__ s,
                                                      unsigned short* __restrict__ ab) {
  int row = blockIdx.x;
  int b = row >> 11, i = row & 2047;
  float* p = s + (size_t)b*Tn*Tn + (size_t)i*Tn;
  unsigned short* a = ab + ((size_t)b*Tn + i) * Tn;
  int len = i + 1;
  int padEnd = ((i >> 7) + 1) << 7;
  int tid = threadIdx.x;
  __shared__ float redm[4];
  __shared__ float reds[4];
  float m = -1e30f;
  for (int j = tid; j < len; j += 256) m = fmaxf(m, p[j]);
#pragma unroll
  for (int off = 32; off > 0; off >>= 1) m = fmaxf(m, __shfl_down(m, off));
  if ((tid & 63) == 0) redm[tid >> 6] = m;
  __syncthreads();
  if (tid == 0) redm[0] = fmaxf(fmaxf(redm[0], redm[1]), fmaxf(redm[2], redm[3]));
  __syncthreads();
  m = redm[0];
  float sum = 0.0f;
  for (int j = tid; j < len; j += 256) {
    float e = __expf(p[j] - m);
    p[j] = e;
    sum += e;
  }
#pragma unroll
  for (int off = 32; off > 0; off >>= 1) sum += __shfl_down(sum, off);
  if ((tid & 63) == 0) reds[tid >> 6] = sum;
  __syncthreads();
  if (tid == 0) reds[0] = reds[0] + reds[1] + reds[2] + reds[3];
  __syncthreads();
  float inv = 1.0f / reds[0];
  for (int j = tid; j < len; j += 256) a[j] = f2bf(p[j] * inv);
  for (int j = len + tid; j < padEnd; j += 256) a[j] = 0;
}

// ---------------- ctx = attn_bf16 @ vT^T  (bf16 MFMA, causal K bound) --------
__global__ __launch_bounds__(256) void ctx_kernel(const unsigned short* __restrict__ ab,
                                                  const unsigned short* __restrict__ vT,
                                                  unsigned short* __restrict__ ctxb) {
  __shared__ unsigned short a_lds[128 * 40];
  __shared__ unsigned short b_lds[128 * 40];
  int b = blockIdx.z;
  int n0 = blockIdx.x * 128, m0 = blockIdx.y * 128;
  int kmax = (blockIdx.y + 1) * 128;
  const unsigned short* A  = ab + (size_t)b * Tn * Tn;
  const unsigned short* Bw = vT + (size_t)b * Hn * Tn;
  int tid = threadIdx.x;
  int wid = tid >> 6, lane = tid & 63;
  int wm = wid >> 1, wn = wid & 1;
  f32x4 acc[4][4];
#pragma unroll
  for (int mf = 0; mf < 4; ++mf)
#pragma unroll
    for (int nf = 0; nf < 4; ++nf) {
      acc[mf][nf][0] = 0.0f; acc[mf][nf][1] = 0.0f;
      acc[mf][nf][2] = 0.0f; acc[mf][nf][3] = 0.0f;
    }
  int kcol = (lane >> 4) * 8;
  int rbase = lane & 15;
  for (int k0 = 0; k0 < kmax; k0 += 32) {
#pragma unroll
    for (int sidx = 0; sidx < 2; ++sidx) {
      int slot = tid + sidx * 256;
      int row = slot >> 2, c8 = (slot & 3) * 8;
      uint4 av = *(const uint4*)(A  + (size_t)(m0 + row) * Tn + k0 + c8);
      *(uint4*)&a_lds[row * 40 + c8] = av;
      uint4 bv = *(const uint4*)(Bw + (size_t)(n0 + row) * Tn + k0 + c8);
      *(uint4*)&b_lds[row * 40 + c8] = bv;
    }
    __syncthreads();
    bf16x8 af[4], bf[4];
#pragma unroll
    for (int mf = 0; mf < 4; ++mf)
      af[mf] = *(const bf16x8*)&a_lds[(wm*64 + mf*16 + rbase) * 40 + kcol];
#pragma unroll
    for (int nf = 0; nf < 4; ++nf)
      bf[nf] = *(const bf16x8*)&b_lds[(wn*64 + nf*16 + rbase) * 40 + kcol];
#pragma unroll
    for (int mf = 0; mf < 4; ++mf)
#pragma unroll
      for (int nf = 0; nf < 4; ++nf)
        acc[mf][nf] = __builtin_amdgcn_mfma_f32_16x16x32_bf16(af[mf], bf[nf], acc[mf][nf], 0, 0, 0);
    __syncthreads();
  }
  int rgrp = (lane >> 4) * 4;
#pragma unroll
  for (int mf = 0; mf < 4; ++mf)
#pragma unroll
    for (int nf = 0; nf < 4; ++nf) {
      int col = n0 + wn*64 + nf*16 + (lane & 15);
#pragma unroll
      for (int i2 = 0; i2 < 4; ++i2) {
        int row = m0 + wm*64 + mf*16 + rgrp + i2;
        ctxb[((size_t)b*Tn + row) * Hn + col] = f2bf(acc[mf][nf][i2]);
      }
    }
}

// ---------------- logits = ctx_bf16 @ Wfc_bf16^T + bfc  (MFMA 16x16x32) ------
__global__ __launch_bounds__(256) void logits_kernel(const unsigned short* __restrict__ A,
                                                     const unsigned short* __restrict__ Bw,
                                                     const float* __restrict__ bias,
                                                     float* __restrict__ out) {
  __shared__ unsigned short a_lds[128 * 40];
  __shared__ unsigned short b_lds[128 * 40];
  int n0 = blockIdx.x * 128, m0 = blockIdx.y * 128;
  int tid = threadIdx.x;
  int wid = tid >> 6, lane = tid & 63;
  int wm = wid >> 1, wn = wid & 1;
  f32x4 acc[4][4];
#pragma unroll
  for (int mf = 0; mf < 4; ++mf)
#pragma unroll
    for (int nf = 0; nf < 4; ++nf) {
      acc[mf][nf][0] = 0.0f; acc[mf][nf][1] = 0.0f;
      acc[mf][nf][2] = 0.0f; acc[mf][nf][3] = 0.0f;
    }
  int kcol = (lane >> 4) * 8;
  int rbase = lane & 15;
  for (int k0 = 0; k0 < 512; k0 += 32) {
#pragma unroll
    for (int sidx = 0; sidx < 2; ++sidx) {
      int slot = tid + sidx * 256;
      int row = slot >> 2, c8 = (slot & 3) * 8;
      uint4 av = *(const uint4*)(A  + (size_t)(m0 + row) * 512 + k0 + c8);
      *(uint4*)&a_lds[row * 40 + c8] = av;
      uint4 bv = *(const uint4*)(Bw + (size_t)(n0 + row) * 512 + k0 + c8);
      *(uint4*)&b_lds[row * 40 + c8] = bv;
    }
    __syncthreads();
    bf16x8 af[4], bf[4];
#pragma unroll
    for (int mf = 0; mf < 4; ++mf)
      af[mf] = *(const bf16x8*)&a_lds[(wm*64 + mf*16 + rbase) * 40 + kcol];
#pragma unroll
    for (int nf = 0; nf < 4; ++nf)
      bf[nf] = *(const bf16x8*)&b_lds[(wn*64 + nf*16 + rbase) * 40 + kcol];
#pragma unroll
    for (int mf = 0; mf < 4; ++mf)
#pragma unroll
      for (int nf = 0; nf < 4; ++nf)
        acc[mf][nf] = __builtin_amdgcn_mfma_f32_16x16x32_bf16(af[mf], bf[nf], acc[mf][nf], 0, 0, 0);
    __syncthreads();
  }
  int rgrp = (lane >> 4) * 4;
#pragma unroll
  for (int mf = 0; mf < 4; ++mf)
#pragma unroll
    for (int nf = 0; nf < 4; ++nf) {
      int col = n0 + wn*64 + nf*16 + (lane & 15);
      float bc = bias[col];
#pragma unroll
      for (int i2 = 0; i2 < 4; ++i2) {
        int row = m0 + wm*64 + mf*16 + rgrp + i2;
        out[(size_t)row * Vn + col] = acc[mf][nf][i2] + bc;
      }
    }
}

extern "C" void kernel_launch(void* const* d_in, const int* in_sizes, int n_in,
                              void* d_out, int out_size, void* d_ws, size_t ws_size,
                              hipStream_t stream) {
  const int*   x   = (const int*)d_in[0];
  const float* emb = (const float*)d_in[1];
  const float* Wih = (const float*)d_in[2];
  const float* Whh = (const float*)d_in[3];
  const float* bih = (const float*)d_in[4];
  const float* bhh = (const float*)d_in[5];
  const float* Wq  = (const float*)d_in[6];
  const float* bq  = (const float*)d_in[7];
  const float* Wk  = (const float*)d_in[8];
  const float* bk  = (const float*)d_in[9];
  const float* Wv  = (const float*)d_in[10];
  const float* bv  = (const float*)d_in[11];
  const float* Wfc = (const float*)d_in[12];
  const float* bfc = (const float*)d_in[13];
  float* out = (float*)d_out;

  char* ws = (char*)d_ws;
  unsigned short* hsb   = (unsigned short*)(ws);               //  8 MB [0,8M)
  unsigned short* qb    = (unsigned short*)(ws + 8388608);     //  8 MB
  unsigned short* kb    = (unsigned short*)(ws + 16777216);    //  8 MB
  unsigned short* vb    = (unsigned short*)(ws + 25165824);    //  8 MB
  unsigned short* vTb   = (unsigned short*)(ws + 33554432);    //  8 MB
  unsigned short* ctxb  = (unsigned short*)(ws + 41943040);    //  8 MB
  unsigned short* wfcb  = (unsigned short*)(ws + 50331648);    // 32 MB
  unsigned short* embb  = (unsigned short*)(ws + 83886080);    //  8 MB
  unsigned short* wihb  = (unsigned short*)(ws + 92274688);    // 1.5 MB
  unsigned short* wqkvb = (unsigned short*)(ws + 93847552);    // 1.5 MB -> ends ~95.4 MB

  // d_out (1,048,576,000 B) doubles as scratch: scores(fp32) + xg + packed-h +
  // attn(bf16); all fully consumed before logits_kernel overwrites the buffer.
  float* scores = out;                                                         // [0, 67,108,864)
  float* xg = (float*)((char*)d_out + 67108864);                               // 50,331,648 B
  unsigned long long* th = (unsigned long long*)((char*)d_out + 117440512);    // 16,777,216 B
  unsigned short* attnb  = (unsigned short*)((char*)d_out + 150994944);        // 33,554,432 B

  hipMemsetAsync(th, 0, (size_t)Tn * 1024 * 8, stream);       // clear tags (replay-safe)
  prep_kernel<<<19584, 256, 0, stream>>>(Wfc, wfcb, Wih, wihb, Wq, Wk, Wv,
                                         wqkvb, x, emb, embb);
  xg_mm_kernel<<<dim3(12, 64), 256, 0, stream>>>(embb, wihb, bih, xg);
  gru_kernel<<<256, 256, 0, stream>>>(Whh, bhh, xg, hsb, th);
  qkv_mm_kernel<<<dim3(12, 64), 256, 0, stream>>>(hsb, wqkvb, bq, bk, bv, qb, kb, vb);
  vt_kernel<<<dim3(32, 8, Bn), 256, 0, stream>>>(vb, vTb);
  score_kernel<<<dim3(16, 16, Bn), 256, 0, stream>>>(qb, kb, scores);
  softmax_kernel<<<BT, 256, 0, stream>>>(scores, attnb);
  ctx_kernel<<<dim3(4, 16, Bn), 256, 0, stream>>>(attnb, vTb, ctxb);
  logits_kernel<<<dim3(250, 64), 256, 0, stream>>>(ctxb, wfcb, bfc, out);
}